// Round 7
// baseline (300.753 us; speedup 1.0000x reference)
//
#include <hip/hip_runtime.h>

#define ALPHA 0.5f
#define BETA 0.5f
#define SMOOTH 1e-6f

constexpr int kB = 32, kC = 4, kH = 512, kW = 512;
constexpr int kHW4 = kH * kW / 4;          // 65536
constexpr int kNVEC = kB * kHW4;           // 2097152 float4-groups
constexpr long long kNPIX = (long long)kB * kH * kW;  // 8388608

constexpr int kThreads = 256;
constexpr int kGPT = 4;                               // float4-groups per thread
constexpr int kBlocks = kNVEC / (kThreads * kGPT);    // 2048, exact
constexpr int kQuarter = kNVEC / 4;                   // 524288
constexpr int kTotalWaves = kBlocks * (kThreads / 64);  // 8192

// slots: 0=ce, 1..3=ps0..ps2, 4..7=it0..it3, 8..10=ct0..ct2
constexpr int kSlots = 11;
constexpr int kReps = 64;          // one replica per lane of the finalize wave
constexpr unsigned kMagic = 0x5A17C0DEu;

// ws dword layout:
//   [0]            flag (kMagic once initialized)
//   [16]           wave-completion counter
//   [64 + s*1024 + r*16]  accumulator slot s, replica r  (64B per replica)

__device__ __forceinline__ float dpp_wave_sum(float x) {
    int t;
    t = __builtin_amdgcn_update_dpp(0, __builtin_bit_cast(int, x), 0x111, 0xF, 0xF, true);
    x += __builtin_bit_cast(float, t);
    t = __builtin_amdgcn_update_dpp(0, __builtin_bit_cast(int, x), 0x112, 0xF, 0xF, true);
    x += __builtin_bit_cast(float, t);
    t = __builtin_amdgcn_update_dpp(0, __builtin_bit_cast(int, x), 0x114, 0xF, 0xF, true);
    x += __builtin_bit_cast(float, t);
    t = __builtin_amdgcn_update_dpp(0, __builtin_bit_cast(int, x), 0x118, 0xF, 0xF, true);
    x += __builtin_bit_cast(float, t);
    t = __builtin_amdgcn_update_dpp(0, __builtin_bit_cast(int, x), 0x142, 0xF, 0xF, true);
    x += __builtin_bit_cast(float, t);
    t = __builtin_amdgcn_update_dpp(0, __builtin_bit_cast(int, x), 0x143, 0xF, 0xF, true);
    x += __builtin_bit_cast(float, t);
    return x;   // lane 63 holds the wave sum
}

__device__ __forceinline__ int dpp_wave_sum_i(int x) {
    int t;
    t = __builtin_amdgcn_update_dpp(0, x, 0x111, 0xF, 0xF, true); x += t;
    t = __builtin_amdgcn_update_dpp(0, x, 0x112, 0xF, 0xF, true); x += t;
    t = __builtin_amdgcn_update_dpp(0, x, 0x114, 0xF, 0xF, true); x += t;
    t = __builtin_amdgcn_update_dpp(0, x, 0x118, 0xF, 0xF, true); x += t;
    t = __builtin_amdgcn_update_dpp(0, x, 0x142, 0xF, 0xF, true); x += t;
    t = __builtin_amdgcn_update_dpp(0, x, 0x143, 0xF, 0xF, true); x += t;
    return x;
}

__device__ __forceinline__ float ws_load(const float* p) {
    return __hip_atomic_load(p, __ATOMIC_RELAXED, __HIP_MEMORY_SCOPE_AGENT);
}
__device__ __forceinline__ void ws_store(float* p, float v) {
    __hip_atomic_store(p, v, __ATOMIC_RELAXED, __HIP_MEMORY_SCOPE_AGENT);
}

__global__ __launch_bounds__(kThreads, 2) void loss_fused(const float* __restrict__ logits,
                                                          const int* __restrict__ tgt,
                                                          float* __restrict__ ws,
                                                          float* __restrict__ out) {
    unsigned* flag = reinterpret_cast<unsigned*>(ws);
    unsigned* cnt  = reinterpret_cast<unsigned*>(ws) + 16;
    float* A = ws + 64;

    // ---- First-call (or post-poison) init: block 0 thread 0 zeroes state ----
    if (blockIdx.x == 0 && threadIdx.x == 0) {
        if (__hip_atomic_load(flag, __ATOMIC_RELAXED, __HIP_MEMORY_SCOPE_AGENT) != kMagic) {
            for (int s = 0; s < kSlots; ++s)
                for (int r = 0; r < kReps; ++r)
                    ws_store(&A[s * 1024 + r * 16], 0.f);
            __hip_atomic_store(cnt, 0u, __ATOMIC_RELAXED, __HIP_MEMORY_SCOPE_AGENT);
            asm volatile("s_waitcnt vmcnt(0)" ::: "memory");
            __hip_atomic_store(flag, kMagic, __ATOMIC_RELAXED, __HIP_MEMORY_SCOPE_AGENT);
        }
    }

    const int tid = blockIdx.x * kThreads + threadIdx.x;   // 0..kQuarter-1
    const float4* lg4 = reinterpret_cast<const float4*>(logits);
    const int4*   tg4 = reinterpret_cast<const int4*>(tgt);

    // 4 groups, one per 8-image stripe: 20 independent loads in flight.
    float4 X0[kGPT], X1[kGPT], X2[kGPT], X3[kGPT];
    int4   T[kGPT];
    #pragma unroll
    for (int k = 0; k < kGPT; ++k) {
        const int v = tid + k * kQuarter;
        const int b = v >> 16;
        const int hw = v & (kHW4 - 1);
        const int base = b * (kC * kHW4) + hw;
        X0[k] = lg4[base];
        X1[k] = lg4[base + kHW4];
        X2[k] = lg4[base + 2 * kHW4];
        X3[k] = lg4[base + 3 * kHW4];
        T[k]  = tg4[v];
    }

    float ce = 0.f;
    float ps0 = 0.f, ps1 = 0.f, ps2 = 0.f;
    float it0 = 0.f, it1 = 0.f, it2 = 0.f, it3 = 0.f;
    int cntA = 0;   // class0 in bits 0..15, class1 in bits 16..31
    int cntB = 0;   // class2

    auto px = [&](float x0, float x1, float x2, float x3, int t) {
        // logits ~ N(0,1): exp without max-subtraction is fp32-safe
        float e0 = __expf(x0);
        float e1 = __expf(x1);
        float e2 = __expf(x2);
        float e3 = __expf(x3);
        float se = e0 + e1 + e2 + e3;
        float inv = __builtin_amdgcn_rcpf(se);
        float xt = (t == 0) ? x0 : (t == 1) ? x1 : (t == 2) ? x2 : x3;
        ce += __logf(se) - xt;
        float p0 = e0 * inv, p1 = e1 * inv, p2 = e2 * inv, p3 = e3 * inv;
        ps0 += p0; ps1 += p1; ps2 += p2;
        it0 += (t == 0) ? p0 : 0.f;
        it1 += (t == 1) ? p1 : 0.f;
        it2 += (t == 2) ? p2 : 0.f;
        it3 += (t == 3) ? p3 : 0.f;
        cntA += (t == 0) ? 1 : 0;
        cntA += (t == 1) ? 0x10000 : 0;
        cntB += (t == 2) ? 1 : 0;
    };
    #pragma unroll
    for (int k = 0; k < kGPT; ++k) {
        px(X0[k].x, X1[k].x, X2[k].x, X3[k].x, T[k].x);
        px(X0[k].y, X1[k].y, X2[k].y, X3[k].y, T[k].y);
        px(X0[k].z, X1[k].z, X2[k].z, X3[k].z, T[k].z);
        px(X0[k].w, X1[k].w, X2[k].w, X3[k].w, T[k].w);
    }

    // ---- Wave reduction (VALU DPP, no barriers, no LDS) ----
    float r[kSlots];
    r[0] = dpp_wave_sum(ce);
    r[1] = dpp_wave_sum(ps0);
    r[2] = dpp_wave_sum(ps1);
    r[3] = dpp_wave_sum(ps2);
    r[4] = dpp_wave_sum(it0);
    r[5] = dpp_wave_sum(it1);
    r[6] = dpp_wave_sum(it2);
    r[7] = dpp_wave_sum(it3);
    int rA = dpp_wave_sum_i(cntA);
    int rB = dpp_wave_sum_i(cntB);
    r[8]  = (float)(rA & 0xffff);
    r[9]  = (float)(rA >> 16);
    r[10] = (float)(rB & 0xffff);

    const int lane = threadIdx.x & 63;
    const int gwave = blockIdx.x * (kThreads / 64) + (threadIdx.x >> 6);
    const int rep = gwave & (kReps - 1);

    unsigned ticket = 0;
    if (lane == 63) {
        // Ensure init has been published (1 iteration in steady state).
        while (__hip_atomic_load(flag, __ATOMIC_RELAXED, __HIP_MEMORY_SCOPE_AGENT) != kMagic) {}
        #pragma unroll
        for (int s = 0; s < kSlots; ++s)
            atomicAdd(&A[s * 1024 + rep * 16], r[s]);
        // All partial adds globally visible before taking a ticket.
        asm volatile("s_waitcnt vmcnt(0)" ::: "memory");
        ticket = __hip_atomic_fetch_add(cnt, 1u, __ATOMIC_RELAXED, __HIP_MEMORY_SCOPE_AGENT);
    }
    ticket = (unsigned)__shfl((int)ticket, 63);

    // ---- Last wave finalizes: read replicas lane-parallel, reduce, output, reset ----
    if (ticket == (unsigned)(kTotalWaves - 1)) {
        float tot[kSlots];
        #pragma unroll
        for (int s = 0; s < kSlots; ++s) {
            float v = ws_load(&A[s * 1024 + lane * 16]);
            tot[s] = dpp_wave_sum(v);   // total in lane 63
        }
        if (lane == 63) {
            float npix = (float)kNPIX;
            float ce_m = tot[0] / npix;
            float ps[4] = {tot[1], tot[2], tot[3], npix - tot[1] - tot[2] - tot[3]};
            float it[4] = {tot[4], tot[5], tot[6], tot[7]};
            float ct[4] = {tot[8], tot[9], tot[10], npix - tot[8] - tot[9] - tot[10]};
            float dsum = 0.f;
            #pragma unroll
            for (int c = 0; c < 4; ++c) {
                float U = ps[c] + ct[c];
                dsum += 1.f - (2.f * it[c] + SMOOTH) / (U + SMOOTH);
            }
            float dice = dsum * 0.25f;
            out[0] = ALPHA * ce_m + BETA * dice;
            out[1] = 1.f - dice;
        }
        // Reset state for the next graph replay (each lane resets its replica).
        #pragma unroll
        for (int s = 0; s < kSlots; ++s)
            ws_store(&A[s * 1024 + lane * 16], 0.f);
        if (lane == 63)
            __hip_atomic_store(cnt, 0u, __ATOMIC_RELAXED, __HIP_MEMORY_SCOPE_AGENT);
    }
}

extern "C" void kernel_launch(void* const* d_in, const int* in_sizes, int n_in,
                              void* d_out, int out_size, void* d_ws, size_t ws_size,
                              hipStream_t stream) {
    const float* logits = (const float*)d_in[0];
    const int*   tgt    = (const int*)d_in[1];
    float* out = (float*)d_out;
    float* ws  = (float*)d_ws;

    loss_fused<<<kBlocks, kThreads, 0, stream>>>(logits, tgt, ws, out);
}

// Round 8
// 43.937 us; speedup vs baseline: 6.8451x; 6.8451x over previous
//
#include <hip/hip_runtime.h>

#define ALPHA 0.5f
#define BETA 0.5f
#define SMOOTH 1e-6f

constexpr int kB = 32, kC = 4, kH = 512, kW = 512;
constexpr int kHW4 = kH * kW / 4;          // 65536
constexpr int kNVEC = kB * kHW4;           // 2097152 float4-groups
constexpr long long kNPIX = (long long)kB * kH * kW;  // 8388608

constexpr int kThreads = 256;
constexpr int kGPT = 8;                               // float4-groups per thread
constexpr int kBlocks = kNVEC / (kThreads * kGPT);    // 1024, exact
constexpr int kStripe = kNVEC / kGPT;                 // 262144 (4-image stripes)

// ws: 11 plane-major partial arrays: ws[slot * kBlocks + block]
// slots: 0=ce, 1..3=ps0..ps2, 4..7=it0..it3, 8..10=ct0..ct2
constexpr int kSlots = 11;

__device__ __forceinline__ float dpp_wave_sum(float x) {
    int t;
    t = __builtin_amdgcn_update_dpp(0, __builtin_bit_cast(int, x), 0x111, 0xF, 0xF, true);
    x += __builtin_bit_cast(float, t);
    t = __builtin_amdgcn_update_dpp(0, __builtin_bit_cast(int, x), 0x112, 0xF, 0xF, true);
    x += __builtin_bit_cast(float, t);
    t = __builtin_amdgcn_update_dpp(0, __builtin_bit_cast(int, x), 0x114, 0xF, 0xF, true);
    x += __builtin_bit_cast(float, t);
    t = __builtin_amdgcn_update_dpp(0, __builtin_bit_cast(int, x), 0x118, 0xF, 0xF, true);
    x += __builtin_bit_cast(float, t);
    t = __builtin_amdgcn_update_dpp(0, __builtin_bit_cast(int, x), 0x142, 0xF, 0xF, true);
    x += __builtin_bit_cast(float, t);
    t = __builtin_amdgcn_update_dpp(0, __builtin_bit_cast(int, x), 0x143, 0xF, 0xF, true);
    x += __builtin_bit_cast(float, t);
    return x;   // lane 63 holds the wave sum
}

__device__ __forceinline__ int dpp_wave_sum_i(int x) {
    int t;
    t = __builtin_amdgcn_update_dpp(0, x, 0x111, 0xF, 0xF, true); x += t;
    t = __builtin_amdgcn_update_dpp(0, x, 0x112, 0xF, 0xF, true); x += t;
    t = __builtin_amdgcn_update_dpp(0, x, 0x114, 0xF, 0xF, true); x += t;
    t = __builtin_amdgcn_update_dpp(0, x, 0x118, 0xF, 0xF, true); x += t;
    t = __builtin_amdgcn_update_dpp(0, x, 0x142, 0xF, 0xF, true); x += t;
    t = __builtin_amdgcn_update_dpp(0, x, 0x143, 0xF, 0xF, true); x += t;
    return x;
}

__global__ __launch_bounds__(kThreads, 1) void loss_main(const float* __restrict__ logits,
                                                         const int* __restrict__ tgt,
                                                         float* __restrict__ ws) {
    const int tid = blockIdx.x * kThreads + threadIdx.x;   // 0..kStripe-1
    const float4* lg4 = reinterpret_cast<const float4*>(logits);
    const int4*   tg4 = reinterpret_cast<const int4*>(tgt);

    // 8 groups, one per 4-image stripe: 40 independent loads in flight.
    float4 X0[kGPT], X1[kGPT], X2[kGPT], X3[kGPT];
    int4   T[kGPT];
    #pragma unroll
    for (int k = 0; k < kGPT; ++k) {
        const int v = tid + k * kStripe;        // compile-time k => static offsets
        const int b = v >> 16;
        const int hw = v & (kHW4 - 1);
        const int base = b * (kC * kHW4) + hw;
        X0[k] = lg4[base];
        X1[k] = lg4[base + kHW4];
        X2[k] = lg4[base + 2 * kHW4];
        X3[k] = lg4[base + 3 * kHW4];
        T[k]  = tg4[v];
    }

    float ce = 0.f;
    float ps0 = 0.f, ps1 = 0.f, ps2 = 0.f;
    float it0 = 0.f, it1 = 0.f, it2 = 0.f, it3 = 0.f;
    int cntA = 0;   // class0 in bits 0..15, class1 in bits 16..31
    int cntB = 0;   // class2

    auto px = [&](float x0, float x1, float x2, float x3, int t) {
        // logits ~ N(0,1): exp without max-subtraction is fp32-safe
        float e0 = __expf(x0);
        float e1 = __expf(x1);
        float e2 = __expf(x2);
        float e3 = __expf(x3);
        float se = e0 + e1 + e2 + e3;
        float inv = __builtin_amdgcn_rcpf(se);
        float xt = (t == 0) ? x0 : (t == 1) ? x1 : (t == 2) ? x2 : x3;
        ce += __logf(se) - xt;
        float p0 = e0 * inv, p1 = e1 * inv, p2 = e2 * inv, p3 = e3 * inv;
        ps0 += p0; ps1 += p1; ps2 += p2;
        it0 += (t == 0) ? p0 : 0.f;
        it1 += (t == 1) ? p1 : 0.f;
        it2 += (t == 2) ? p2 : 0.f;
        it3 += (t == 3) ? p3 : 0.f;
        cntA += (t == 0) ? 1 : 0;
        cntA += (t == 1) ? 0x10000 : 0;
        cntB += (t == 2) ? 1 : 0;
    };
    #pragma unroll
    for (int k = 0; k < kGPT; ++k) {
        px(X0[k].x, X1[k].x, X2[k].x, X3[k].x, T[k].x);
        px(X0[k].y, X1[k].y, X2[k].y, X3[k].y, T[k].y);
        px(X0[k].z, X1[k].z, X2[k].z, X3[k].z, T[k].z);
        px(X0[k].w, X1[k].w, X2[k].w, X3[k].w, T[k].w);
    }

    // ---- Wave reduction (VALU DPP, no barriers) ----
    float r[kSlots];
    r[0] = dpp_wave_sum(ce);
    r[1] = dpp_wave_sum(ps0);
    r[2] = dpp_wave_sum(ps1);
    r[3] = dpp_wave_sum(ps2);
    r[4] = dpp_wave_sum(it0);
    r[5] = dpp_wave_sum(it1);
    r[6] = dpp_wave_sum(it2);
    r[7] = dpp_wave_sum(it3);
    int rA = dpp_wave_sum_i(cntA);
    int rB = dpp_wave_sum_i(cntB);
    r[8]  = (float)(rA & 0xffff);
    r[9]  = (float)(rA >> 16);
    r[10] = (float)(rB & 0xffff);

    // ---- Cross-wave combine in LDS, then one plain store per slot ----
    __shared__ float smem[4][kSlots];
    const int lane = threadIdx.x & 63;
    const int wave = threadIdx.x >> 6;
    if (lane == 63) {
        #pragma unroll
        for (int i = 0; i < kSlots; ++i) smem[wave][i] = r[i];
    }
    __syncthreads();
    if (threadIdx.x < kSlots) {
        float s = smem[0][threadIdx.x] + smem[1][threadIdx.x] +
                  smem[2][threadIdx.x] + smem[3][threadIdx.x];
        ws[threadIdx.x * kBlocks + blockIdx.x] = s;   // plain store, no memset needed
    }
}

__global__ __launch_bounds__(1024) void finalize_kernel(const float* __restrict__ ws,
                                                        float* __restrict__ out) {
    // 11 plane-major partial arrays of 1024 floats = 2816 float4 total.
    __shared__ float tot[kSlots];
    if (threadIdx.x < kSlots) tot[threadIdx.x] = 0.f;
    __syncthreads();

    const float4* ws4 = reinterpret_cast<const float4*>(ws);
    constexpr int kVecPerPlane = kBlocks / 4;          // 256
    constexpr int kVecTotal = kSlots * kVecPerPlane;   // 2816
    for (int g = threadIdx.x; g < kVecTotal; g += 1024) {
        float4 v = ws4[g];
        atomicAdd(&tot[g >> 8], (v.x + v.y) + (v.z + v.w));
    }
    __syncthreads();

    if (threadIdx.x == 0) {
        float npix = (float)kNPIX;
        float ce_m = tot[0] / npix;
        float ps[4] = {tot[1], tot[2], tot[3], npix - tot[1] - tot[2] - tot[3]};
        float it[4] = {tot[4], tot[5], tot[6], tot[7]};
        float ct[4] = {tot[8], tot[9], tot[10], npix - tot[8] - tot[9] - tot[10]};
        float dsum = 0.f;
        #pragma unroll
        for (int c = 0; c < 4; ++c) {
            float U = ps[c] + ct[c];
            dsum += 1.f - (2.f * it[c] + SMOOTH) / (U + SMOOTH);
        }
        float dice = dsum * 0.25f;
        out[0] = ALPHA * ce_m + BETA * dice;
        out[1] = 1.f - dice;
    }
}

extern "C" void kernel_launch(void* const* d_in, const int* in_sizes, int n_in,
                              void* d_out, int out_size, void* d_ws, size_t ws_size,
                              hipStream_t stream) {
    const float* logits = (const float*)d_in[0];
    const int*   tgt    = (const int*)d_in[1];
    float* out = (float*)d_out;
    float* ws  = (float*)d_ws;

    loss_main<<<kBlocks, kThreads, 0, stream>>>(logits, tgt, ws);
    finalize_kernel<<<1, 1024, 0, stream>>>(ws, out);
}

// Round 9
// 33.250 us; speedup vs baseline: 9.0452x; 1.3214x over previous
//
#include <hip/hip_runtime.h>

#define ALPHA 0.5f
#define BETA 0.5f
#define SMOOTH 1e-6f

constexpr int kB = 32, kC = 4, kH = 512, kW = 512;
constexpr int kHW4 = kH * kW / 4;          // 65536
constexpr int kNVEC = kB * kHW4;           // 2097152 float4-groups
constexpr long long kNPIX = (long long)kB * kH * kW;  // 8388608

constexpr int kThreads = 256;
constexpr int kGPT = 4;                               // float4-groups per thread
constexpr int kBlocks = kNVEC / (kThreads * kGPT);    // 2048, exact
constexpr int kQuarter = kNVEC / 4;                   // 524288

constexpr float kLog2e = 1.4426950408889634f;   // log2(e)
constexpr float kLn2   = 0.6931471805599453f;   // ln(2)

// ws: 11 plane-major partial arrays: ws[slot * kBlocks + block]
// slots: 0=ce(log2 units), 1..3=ps0..ps2, 4..7=it0..it3, 8..10=ct0..ct2
constexpr int kSlots = 11;

__device__ __forceinline__ float dpp_wave_sum(float x) {
    int t;
    t = __builtin_amdgcn_update_dpp(0, __builtin_bit_cast(int, x), 0x111, 0xF, 0xF, true);
    x += __builtin_bit_cast(float, t);
    t = __builtin_amdgcn_update_dpp(0, __builtin_bit_cast(int, x), 0x112, 0xF, 0xF, true);
    x += __builtin_bit_cast(float, t);
    t = __builtin_amdgcn_update_dpp(0, __builtin_bit_cast(int, x), 0x114, 0xF, 0xF, true);
    x += __builtin_bit_cast(float, t);
    t = __builtin_amdgcn_update_dpp(0, __builtin_bit_cast(int, x), 0x118, 0xF, 0xF, true);
    x += __builtin_bit_cast(float, t);
    t = __builtin_amdgcn_update_dpp(0, __builtin_bit_cast(int, x), 0x142, 0xF, 0xF, true);
    x += __builtin_bit_cast(float, t);
    t = __builtin_amdgcn_update_dpp(0, __builtin_bit_cast(int, x), 0x143, 0xF, 0xF, true);
    x += __builtin_bit_cast(float, t);
    return x;   // lane 63 holds the wave sum
}

__device__ __forceinline__ int dpp_wave_sum_i(int x) {
    int t;
    t = __builtin_amdgcn_update_dpp(0, x, 0x111, 0xF, 0xF, true); x += t;
    t = __builtin_amdgcn_update_dpp(0, x, 0x112, 0xF, 0xF, true); x += t;
    t = __builtin_amdgcn_update_dpp(0, x, 0x114, 0xF, 0xF, true); x += t;
    t = __builtin_amdgcn_update_dpp(0, x, 0x118, 0xF, 0xF, true); x += t;
    t = __builtin_amdgcn_update_dpp(0, x, 0x142, 0xF, 0xF, true); x += t;
    t = __builtin_amdgcn_update_dpp(0, x, 0x143, 0xF, 0xF, true); x += t;
    return x;
}

__global__ __launch_bounds__(kThreads, 2) void loss_main(const float* __restrict__ logits,
                                                         const int* __restrict__ tgt,
                                                         float* __restrict__ ws) {
    const int tid = blockIdx.x * kThreads + threadIdx.x;   // 0..kQuarter-1
    const float4* lg4 = reinterpret_cast<const float4*>(logits);
    const int4*   tg4 = reinterpret_cast<const int4*>(tgt);

    // 4 groups, one per 8-image stripe: 20 independent loads in flight.
    float4 X0[kGPT], X1[kGPT], X2[kGPT], X3[kGPT];
    int4   T[kGPT];
    #pragma unroll
    for (int k = 0; k < kGPT; ++k) {
        const int v = tid + k * kQuarter;       // compile-time k => static offsets
        const int b = v >> 16;
        const int hw = v & (kHW4 - 1);
        const int base = b * (kC * kHW4) + hw;
        X0[k] = lg4[base];
        X1[k] = lg4[base + kHW4];
        X2[k] = lg4[base + 2 * kHW4];
        X3[k] = lg4[base + 3 * kHW4];
        T[k]  = tg4[v];
    }

    float ce2 = 0.f;   // CE partial in log2 units; multiply by ln2 in finalize
    float ps0 = 0.f, ps1 = 0.f, ps2 = 0.f;
    float it0 = 0.f, it1 = 0.f, it2 = 0.f, it3 = 0.f;
    int cntA = 0;   // class0 in bits 0..15, class1 in bits 16..31
    int cntB = 0;   // class2

    auto px = [&](float x0, float x1, float x2, float x3, int t) {
        // log2-domain softmax (logits ~ N(0,1): no max-subtraction needed).
        float y0 = x0 * kLog2e;
        float y1 = x1 * kLog2e;
        float y2 = x2 * kLog2e;
        float y3 = x3 * kLog2e;
        float e0 = __builtin_amdgcn_exp2f(y0);
        float e1 = __builtin_amdgcn_exp2f(y1);
        float e2 = __builtin_amdgcn_exp2f(y2);
        float e3 = __builtin_amdgcn_exp2f(y3);
        float se = (e0 + e1) + (e2 + e3);
        float inv = __builtin_amdgcn_rcpf(se);
        float lg = __builtin_amdgcn_logf(se);       // log2(se)
        bool c0 = (t == 0), c1 = (t == 1), c2 = (t == 2), c3 = (t == 3);
        float yt = c0 ? y0 : c1 ? y1 : c2 ? y2 : y3;
        float et = c0 ? e0 : c1 ? e1 : c2 ? e2 : e3;
        ce2 += lg - yt;
        float pt = et * inv;                         // prob of target class
        ps0 = __builtin_fmaf(e0, inv, ps0);
        ps1 = __builtin_fmaf(e1, inv, ps1);
        ps2 = __builtin_fmaf(e2, inv, ps2);
        it0 += c0 ? pt : 0.f;
        it1 += c1 ? pt : 0.f;
        it2 += c2 ? pt : 0.f;
        it3 += c3 ? pt : 0.f;
        cntA += c0 ? 1 : 0;
        cntA += c1 ? 0x10000 : 0;
        cntB += c2 ? 1 : 0;
    };
    #pragma unroll
    for (int k = 0; k < kGPT; ++k) {
        px(X0[k].x, X1[k].x, X2[k].x, X3[k].x, T[k].x);
        px(X0[k].y, X1[k].y, X2[k].y, X3[k].y, T[k].y);
        px(X0[k].z, X1[k].z, X2[k].z, X3[k].z, T[k].z);
        px(X0[k].w, X1[k].w, X2[k].w, X3[k].w, T[k].w);
    }

    // ---- Wave reduction (VALU DPP, no barriers) ----
    float r[kSlots];
    r[0] = dpp_wave_sum(ce2);
    r[1] = dpp_wave_sum(ps0);
    r[2] = dpp_wave_sum(ps1);
    r[3] = dpp_wave_sum(ps2);
    r[4] = dpp_wave_sum(it0);
    r[5] = dpp_wave_sum(it1);
    r[6] = dpp_wave_sum(it2);
    r[7] = dpp_wave_sum(it3);
    int rA = dpp_wave_sum_i(cntA);
    int rB = dpp_wave_sum_i(cntB);
    r[8]  = (float)(rA & 0xffff);
    r[9]  = (float)(rA >> 16);
    r[10] = (float)(rB & 0xffff);

    // ---- Cross-wave combine in LDS, then one plain store per slot ----
    __shared__ float smem[4][kSlots];
    const int lane = threadIdx.x & 63;
    const int wave = threadIdx.x >> 6;
    if (lane == 63) {
        #pragma unroll
        for (int i = 0; i < kSlots; ++i) smem[wave][i] = r[i];
    }
    __syncthreads();
    if (threadIdx.x < kSlots) {
        float s = smem[0][threadIdx.x] + smem[1][threadIdx.x] +
                  smem[2][threadIdx.x] + smem[3][threadIdx.x];
        ws[threadIdx.x * kBlocks + blockIdx.x] = s;   // plain store, no memset needed
    }
}

__global__ __launch_bounds__(512) void finalize_kernel(const float* __restrict__ ws,
                                                       float* __restrict__ out) {
    // 11 slot-planes of 2048 floats; each thread reads one float4 per plane.
    const float4* ws4 = reinterpret_cast<const float4*>(ws);
    constexpr int kVecPerPlane = kBlocks / 4;   // 512
    float vals[kSlots];
    #pragma unroll
    for (int s = 0; s < kSlots; ++s) {
        float4 v = ws4[s * kVecPerPlane + threadIdx.x];
        vals[s] = dpp_wave_sum((v.x + v.y) + (v.z + v.w));
    }
    __shared__ float smem[8][kSlots];
    const int lane = threadIdx.x & 63;
    const int wave = threadIdx.x >> 6;
    if (lane == 63) {
        #pragma unroll
        for (int s = 0; s < kSlots; ++s) smem[wave][s] = vals[s];
    }
    __syncthreads();
    if (threadIdx.x == 0) {
        float tot[kSlots];
        #pragma unroll
        for (int s = 0; s < kSlots; ++s) {
            float acc = 0.f;
            #pragma unroll
            for (int w = 0; w < 8; ++w) acc += smem[w][s];
            tot[s] = acc;
        }
        float npix = (float)kNPIX;
        float ce_m = tot[0] * kLn2 / npix;          // undo log2 domain
        float ps[4] = {tot[1], tot[2], tot[3], npix - tot[1] - tot[2] - tot[3]};
        float it[4] = {tot[4], tot[5], tot[6], tot[7]};
        float ct[4] = {tot[8], tot[9], tot[10], npix - tot[8] - tot[9] - tot[10]};
        float dsum = 0.f;
        #pragma unroll
        for (int c = 0; c < 4; ++c) {
            float U = ps[c] + ct[c];
            dsum += 1.f - (2.f * it[c] + SMOOTH) / (U + SMOOTH);
        }
        float dice = dsum * 0.25f;
        out[0] = ALPHA * ce_m + BETA * dice;
        out[1] = 1.f - dice;
    }
}

extern "C" void kernel_launch(void* const* d_in, const int* in_sizes, int n_in,
                              void* d_out, int out_size, void* d_ws, size_t ws_size,
                              hipStream_t stream) {
    const float* logits = (const float*)d_in[0];
    const int*   tgt    = (const int*)d_in[1];
    float* out = (float*)d_out;
    float* ws  = (float*)d_ws;

    loss_main<<<kBlocks, kThreads, 0, stream>>>(logits, tgt, ws);
    finalize_kernel<<<1, 512, 0, stream>>>(ws, out);
}